// Round 9
// baseline (399.177 us; speedup 1.0000x reference)
//
#include <hip/hip_runtime.h>

#define NN 100000
#define D 64
#define BN_EPS 1e-5f

typedef unsigned short ushort_t;
typedef unsigned int uint_t;

__device__ __forceinline__ ushort_t f2b_rne(float f) {
    uint_t u = __float_as_uint(f);
    uint_t r = (u + 0x7FFFu + ((u >> 16) & 1u)) >> 16;
    return (ushort_t)r;
}
__device__ __forceinline__ float b2f(ushort_t u) {
    return __uint_as_float(((uint_t)u) << 16);
}

// ================= CSR build =================

__global__ void k_zero(int* cnt, float* sums8, int n) {
    int i = blockIdx.x * blockDim.x + threadIdx.x;
    if (i < n) cnt[i] = 0;
    if (i < 1152) sums8[i] = 0.0f;  // 8*128 slots + 128 final
}

__global__ void k_count4(const int* __restrict__ src, const int* __restrict__ dst,
                         int* cnt, int E) {
    int t = blockIdx.x * blockDim.x + threadIdx.x;
    int e0 = t * 4;
    if (e0 >= E) return;
    if (e0 + 4 <= E) {
        int4 s4 = *(const int4*)(src + e0);
        int4 d4 = *(const int4*)(dst + e0);
        if (s4.x != d4.x) atomicAdd(&cnt[d4.x], 1);
        if (s4.y != d4.y) atomicAdd(&cnt[d4.y], 1);
        if (s4.z != d4.z) atomicAdd(&cnt[d4.z], 1);
        if (s4.w != d4.w) atomicAdd(&cnt[d4.w], 1);
    } else {
        for (int e = e0; e < E; ++e) {
            int s = src[e], d = dst[e];
            if (s != d) atomicAdd(&cnt[d], 1);
        }
    }
}

__global__ void k_dinv_i(const int* __restrict__ cnt, float* dinv, int n) {
    int i = blockIdx.x * blockDim.x + threadIdx.x;
    if (i < n) dinv[i] = rsqrtf((float)cnt[i] + 1.0f);  // +1 self loop
}

// bf16 premultiplied table: xb[i][c] = bf16(x[i][c] * dinv[i])
__global__ void k_xb(const float* __restrict__ x, const float* __restrict__ dinv,
                     ushort_t* __restrict__ xb, int n) {
    int i = blockIdx.x * blockDim.x + threadIdx.x;  // 4 channels per thread
    int total = n * (D / 4);
    if (i >= total) return;
    int row = i >> 4;
    float di = dinv[row];
    float4 v = ((const float4*)x)[i];
    ushort4 o;
    o.x = f2b_rne(v.x * di);
    o.y = f2b_rne(v.y * di);
    o.z = f2b_rne(v.z * di);
    o.w = f2b_rne(v.w * di);
    ((ushort4*)xb)[i] = o;
}

// exclusive scan of cnt -> row_ptr (3 phases)
__global__ __launch_bounds__(1024) void k_scanA(const int* __restrict__ cnt,
                                                int* __restrict__ row_ptr,
                                                int* __restrict__ bsum, int n) {
    __shared__ int sm[1024];
    int tid = threadIdx.x;
    int i = blockIdx.x * 1024 + tid;
    int v = (i < n) ? cnt[i] : 0;
    int xv = v;
    sm[tid] = xv;
    __syncthreads();
    for (int off = 1; off < 1024; off <<= 1) {
        int t = (tid >= off) ? sm[tid - off] : 0;
        __syncthreads();
        xv += t;
        sm[tid] = xv;
        __syncthreads();
    }
    if (i < n) row_ptr[i] = xv - v;
    if (tid == 1023) bsum[blockIdx.x] = xv;
}

__global__ void k_scanB(int* bsum, int nb) {
    __shared__ int sm[128];
    int tid = threadIdx.x;
    int v = (tid < nb) ? bsum[tid] : 0;
    int xv = v;
    sm[tid] = xv;
    __syncthreads();
    for (int off = 1; off < 128; off <<= 1) {
        int t = (tid >= off) ? sm[tid - off] : 0;
        __syncthreads();
        xv += t;
        sm[tid] = xv;
        __syncthreads();
    }
    if (tid < nb) bsum[tid] = xv - v;
}

__global__ void k_scanC(int* __restrict__ row_ptr, int* __restrict__ cursor,
                        const int* __restrict__ bsum, int n) {
    int i = blockIdx.x * blockDim.x + threadIdx.x;
    if (i < n) {
        int r = row_ptr[i] + bsum[i >> 10];
        row_ptr[i] = r;
        cursor[i] = r;
    }
}

__global__ void k_place8(const int* __restrict__ src, const int* __restrict__ dst,
                         int* cursor, int* __restrict__ srcid, int E) {
    int t = blockIdx.x * blockDim.x + threadIdx.x;
    int e0 = t * 8;
    if (e0 >= E) return;
    if (e0 + 8 <= E) {
        int4 sa = *(const int4*)(src + e0);
        int4 sb = *(const int4*)(src + e0 + 4);
        int4 da = *(const int4*)(dst + e0);
        int4 db = *(const int4*)(dst + e0 + 4);
        if (sa.x != da.x) srcid[atomicAdd(&cursor[da.x], 1)] = sa.x;
        if (sa.y != da.y) srcid[atomicAdd(&cursor[da.y], 1)] = sa.y;
        if (sa.z != da.z) srcid[atomicAdd(&cursor[da.z], 1)] = sa.z;
        if (sa.w != da.w) srcid[atomicAdd(&cursor[da.w], 1)] = sa.w;
        if (sb.x != db.x) srcid[atomicAdd(&cursor[db.x], 1)] = sb.x;
        if (sb.y != db.y) srcid[atomicAdd(&cursor[db.y], 1)] = sb.y;
        if (sb.z != db.z) srcid[atomicAdd(&cursor[db.z], 1)] = sb.z;
        if (sb.w != db.w) srcid[atomicAdd(&cursor[db.w], 1)] = sb.w;
    } else {
        for (int e = e0; e < E; ++e) {
            int s = src[e], d = dst[e];
            if (s != d) srcid[atomicAdd(&cursor[d], 1)] = s;
        }
    }
}

// ================= fused gather(bf16) + GEMM + BN stats =================
// agg = did^2 * x_d + did * sum_s xb[s];  one wave per node, lane = channel.
__global__ __launch_bounds__(256) void k_gather_gemm_stats_bf16(
        const int* __restrict__ row_ptr, const int* __restrict__ cnt,
        const int* __restrict__ srcid, const float* __restrict__ x,
        const ushort_t* __restrict__ xb, const float* __restrict__ dinv,
        const float* __restrict__ W, float* __restrict__ out, float* sums8, int n) {
    __shared__ float Ws[64 * 64];
    int tid = threadIdx.x;
    for (int i = tid; i < 64 * 64; i += 256) Ws[i] = W[i];
    __syncthreads();
    int wave = tid >> 6, lane = tid & 63;
    float s = 0.0f, sq = 0.0f;
    for (int d = blockIdx.x * 4 + wave; d < n; d += gridDim.x * 4) {
        int base = row_ptr[d];
        int c = cnt[d];
        float did = dinv[d];
        float self = x[(size_t)d * D + lane];
        float acc = 0.0f;
        int j = 0;
        for (; j + 8 <= c; j += 8) {
            int si[8];
            float xv[8];
#pragma unroll
            for (int u = 0; u < 8; ++u) si[u] = srcid[base + j + u];
#pragma unroll
            for (int u = 0; u < 8; ++u) xv[u] = b2f(xb[(size_t)si[u] * D + lane]);
#pragma unroll
            for (int u = 0; u < 8; ++u) acc += xv[u];
        }
        for (; j < c; ++j) {
            int si = srcid[base + j];
            acc += b2f(xb[(size_t)si * D + lane]);
        }
        float agg = did * (did * self + acc);
        // GEMM: out_row = agg_row @ W
        float o = 0.0f;
#pragma unroll
        for (int k = 0; k < 64; ++k) {
            o += __shfl(agg, k) * Ws[k * 64 + lane];
        }
        out[(size_t)d * D + lane] = o;
        s += o;
        sq += o * o;
    }
    __shared__ float ls[4][64], lq[4][64];
    ls[wave][lane] = s;
    lq[wave][lane] = sq;
    __syncthreads();
    if (wave == 0) {
        float ts = ls[0][lane] + ls[1][lane] + ls[2][lane] + ls[3][lane];
        float tq = lq[0][lane] + lq[1][lane] + lq[2][lane] + lq[3][lane];
        float* slot = sums8 + (size_t)(blockIdx.x & 7) * 128;
        atomicAdd(&slot[lane], ts);
        atomicAdd(&slot[64 + lane], tq);
    }
}

// fp32 CSR gather (fallback when ws too small for xb table)
__global__ __launch_bounds__(256) void k_gather_gemm_stats(
        const int* __restrict__ row_ptr, const int* __restrict__ cnt,
        const int* __restrict__ srcid, const float* __restrict__ x,
        const float* __restrict__ dinv, const float* __restrict__ W,
        float* __restrict__ out, float* sums8, int n) {
    __shared__ float Ws[64 * 64];
    int tid = threadIdx.x;
    for (int i = tid; i < 64 * 64; i += 256) Ws[i] = W[i];
    __syncthreads();
    int wave = tid >> 6, lane = tid & 63;
    float s = 0.0f, sq = 0.0f;
    for (int d = blockIdx.x * 4 + wave; d < n; d += gridDim.x * 4) {
        int base = row_ptr[d];
        int c = cnt[d];
        float did = dinv[d];
        float acc = x[(size_t)d * D + lane] * did * did;
        int j = 0;
        for (; j + 8 <= c; j += 8) {
            int si[8];
            float wv[8], xv[8];
#pragma unroll
            for (int u = 0; u < 8; ++u) si[u] = srcid[base + j + u];
#pragma unroll
            for (int u = 0; u < 8; ++u) wv[u] = dinv[si[u]] * did;
#pragma unroll
            for (int u = 0; u < 8; ++u) xv[u] = x[(size_t)si[u] * D + lane];
#pragma unroll
            for (int u = 0; u < 8; ++u) acc += xv[u] * wv[u];
        }
        for (; j < c; ++j) {
            int si = srcid[base + j];
            acc += x[(size_t)si * D + lane] * (dinv[si] * did);
        }
        float o = 0.0f;
#pragma unroll
        for (int k = 0; k < 64; ++k) {
            o += __shfl(acc, k) * Ws[k * 64 + lane];
        }
        out[(size_t)d * D + lane] = o;
        s += o;
        sq += o * o;
    }
    __shared__ float ls[4][64], lq[4][64];
    ls[wave][lane] = s;
    lq[wave][lane] = sq;
    __syncthreads();
    if (wave == 0) {
        float ts = ls[0][lane] + ls[1][lane] + ls[2][lane] + ls[3][lane];
        float tq = lq[0][lane] + lq[1][lane] + lq[2][lane] + lq[3][lane];
        float* slot = sums8 + (size_t)(blockIdx.x & 7) * 128;
        atomicAdd(&slot[lane], ts);
        atomicAdd(&slot[64 + lane], tq);
    }
}

// fold 8 slots -> final sums (stored at sums8 + 1024)
__global__ void k_finalize(float* sums8) {
    int i = threadIdx.x;  // 128 threads
    float s = 0.0f;
#pragma unroll
    for (int j = 0; j < 8; ++j) s += sums8[j * 128 + i];
    sums8[1024 + i] = s;
}

// ================= BN apply + ReLU (float4, in place) =================
// GCN bias b cancels exactly in BatchNorm: omitted.
__global__ void k_bn_apply(float* out, const float* __restrict__ sums,
                           const float* __restrict__ bnw, const float* __restrict__ bnb,
                           int n) {
    int i = blockIdx.x * blockDim.x + threadIdx.x;
    int total = n * (D / 4);
    if (i >= total) return;
    int c0 = (i * 4) & 63;
    const float invn = 1.0f / (float)NN;
    float4 v = ((const float4*)out)[i];
    float r[4] = {v.x, v.y, v.z, v.w};
#pragma unroll
    for (int j = 0; j < 4; ++j) {
        int c = c0 + j;
        float mean = sums[c] * invn;
        float var = sums[64 + c] * invn - mean * mean;
        if (var < 0.0f) var = 0.0f;
        float scale = bnw[c] * rsqrtf(var + BN_EPS);
        float y = (r[j] - mean) * scale + bnb[c];
        r[j] = y > 0.0f ? y : 0.0f;
    }
    float4 o = {r[0], r[1], r[2], r[3]};
    ((float4*)out)[i] = o;
}

extern "C" void kernel_launch(void* const* d_in, const int* in_sizes, int n_in,
                              void* d_out, int out_size, void* d_ws, size_t ws_size,
                              hipStream_t stream) {
    const float* x = (const float*)d_in[0];
    const int* ei = (const int*)d_in[1];
    const float* W = (const float*)d_in[3];
    const float* bnw = (const float*)d_in[5];
    const float* bnb = (const float*)d_in[6];
    float* out = (float*)d_out;

    const int n = in_sizes[0] / D;   // 100000
    const int E = in_sizes[1] / 2;   // 1600000
    const int* src = ei;
    const int* dst = ei + E;

    const size_t base_words = (size_t)4 * n + (size_t)E + 1280;  // cnt,row,cursor,dinv,srcid,bsum,sums8
    const size_t need_csr = base_words * 4;
    const size_t need_bf16 = need_csr + 16 + (size_t)n * D * 2;

    if (ws_size >= need_csr) {
        int* cnt = (int*)d_ws;
        int* row_ptr = cnt + n;
        int* cursor = row_ptr + n;
        float* dinv = (float*)(cursor + n);
        int* srcid = (int*)(dinv + n);
        int* bsum = srcid + E;                 // 128 ints
        float* sums8 = (float*)(bsum + 128);   // 8*128 slots + 128 final
        float* sums = sums8 + 1024;
        // bf16 table after (16B aligned)
        size_t off = ((size_t)(sums8 + 1152 - (float*)d_ws) * 4 + 15) & ~(size_t)15;
        ushort_t* xb = (ushort_t*)((char*)d_ws + off);

        const int nb = (n + 1023) / 1024;  // 98

        k_zero<<<(n + 255) / 256, 256, 0, stream>>>(cnt, sums8, n);
        k_count4<<<((E + 3) / 4 + 255) / 256, 256, 0, stream>>>(src, dst, cnt, E);
        k_dinv_i<<<(n + 255) / 256, 256, 0, stream>>>(cnt, dinv, n);
        k_scanA<<<nb, 1024, 0, stream>>>(cnt, row_ptr, bsum, n);
        k_scanB<<<1, 128, 0, stream>>>(bsum, nb);
        k_scanC<<<(n + 255) / 256, 256, 0, stream>>>(row_ptr, cursor, bsum, n);
        k_place8<<<((E + 7) / 8 + 255) / 256, 256, 0, stream>>>(src, dst, cursor, srcid, E);

        if (ws_size >= need_bf16) {
            k_xb<<<(n * (D / 4) + 255) / 256, 256, 0, stream>>>(x, dinv, xb, n);
            k_gather_gemm_stats_bf16<<<4096, 256, 0, stream>>>(row_ptr, cnt, srcid, x, xb,
                                                               dinv, W, out, sums8, n);
        } else {
            k_gather_gemm_stats<<<4096, 256, 0, stream>>>(row_ptr, cnt, srcid, x, dinv, W,
                                                          out, sums8, n);
        }
        k_finalize<<<1, 128, 0, stream>>>(sums8);
        k_bn_apply<<<(n * (D / 4) + 255) / 256, 256, 0, stream>>>(out, sums, bnw, bnb, n);
    }
    // (ws_size >= need_csr has held on all prior rounds; no smaller-ws fallback retained)
}

// Round 10
// 373.011 us; speedup vs baseline: 1.0701x; 1.0701x over previous
//
#include <hip/hip_runtime.h>

#define NN 100000
#define D 64
#define BN_EPS 1e-5f

typedef unsigned short ushort_t;
typedef unsigned int uint_t;

__device__ __forceinline__ ushort_t f2b_rne(float f) {
    uint_t u = __float_as_uint(f);
    uint_t r = (u + 0x7FFFu + ((u >> 16) & 1u)) >> 16;
    return (ushort_t)r;
}
__device__ __forceinline__ float b2f_lo(uint_t u) { return __uint_as_float(u << 16); }
__device__ __forceinline__ float b2f_hi(uint_t u) { return __uint_as_float(u & 0xFFFF0000u); }

// ================= CSR build =================

__global__ void k_zero(int* cnt, float* sums16, int n) {
    int i = blockIdx.x * blockDim.x + threadIdx.x;
    if (i < n) cnt[i] = 0;
    if (i < 2176) sums16[i] = 0.0f;  // 16*128 slots + 128 final
}

__global__ void k_count8(const int* __restrict__ src, const int* __restrict__ dst,
                         int* cnt, int E) {
    int t = blockIdx.x * blockDim.x + threadIdx.x;
    int e0 = t * 8;
    if (e0 >= E) return;
    if (e0 + 8 <= E) {
        int4 sa = *(const int4*)(src + e0);
        int4 sb = *(const int4*)(src + e0 + 4);
        int4 da = *(const int4*)(dst + e0);
        int4 db = *(const int4*)(dst + e0 + 4);
        if (sa.x != da.x) atomicAdd(&cnt[da.x], 1);
        if (sa.y != da.y) atomicAdd(&cnt[da.y], 1);
        if (sa.z != da.z) atomicAdd(&cnt[da.z], 1);
        if (sa.w != da.w) atomicAdd(&cnt[da.w], 1);
        if (sb.x != db.x) atomicAdd(&cnt[db.x], 1);
        if (sb.y != db.y) atomicAdd(&cnt[db.y], 1);
        if (sb.z != db.z) atomicAdd(&cnt[db.z], 1);
        if (sb.w != db.w) atomicAdd(&cnt[db.w], 1);
    } else {
        for (int e = e0; e < E; ++e) {
            int s = src[e], d = dst[e];
            if (s != d) atomicAdd(&cnt[d], 1);
        }
    }
}

// fused: dinv[i] = rsqrt(cnt+1); xb[i][c] = bf16(x[i][c] * dinv[i])
__global__ void k_dinv_xb(const int* __restrict__ cnt, const float* __restrict__ x,
                          float* __restrict__ dinv, ushort_t* __restrict__ xb, int n) {
    int i = blockIdx.x * blockDim.x + threadIdx.x;  // 4 channels per thread
    int total = n * (D / 4);
    if (i >= total) return;
    int row = i >> 4;
    float di = rsqrtf((float)cnt[row] + 1.0f);
    if ((i & 15) == 0) dinv[row] = di;
    float4 v = ((const float4*)x)[i];
    ushort4 o;
    o.x = f2b_rne(v.x * di);
    o.y = f2b_rne(v.y * di);
    o.z = f2b_rne(v.z * di);
    o.w = f2b_rne(v.w * di);
    ((ushort4*)xb)[i] = o;
}

// exclusive scan of cnt -> row_ptr (3 phases)
__global__ __launch_bounds__(1024) void k_scanA(const int* __restrict__ cnt,
                                                int* __restrict__ row_ptr,
                                                int* __restrict__ bsum, int n) {
    __shared__ int sm[1024];
    int tid = threadIdx.x;
    int i = blockIdx.x * 1024 + tid;
    int v = (i < n) ? cnt[i] : 0;
    int xv = v;
    sm[tid] = xv;
    __syncthreads();
    for (int off = 1; off < 1024; off <<= 1) {
        int t = (tid >= off) ? sm[tid - off] : 0;
        __syncthreads();
        xv += t;
        sm[tid] = xv;
        __syncthreads();
    }
    if (i < n) row_ptr[i] = xv - v;
    if (tid == 1023) bsum[blockIdx.x] = xv;
}

__global__ void k_scanB(int* bsum, int nb) {
    __shared__ int sm[128];
    int tid = threadIdx.x;
    int v = (tid < nb) ? bsum[tid] : 0;
    int xv = v;
    sm[tid] = xv;
    __syncthreads();
    for (int off = 1; off < 128; off <<= 1) {
        int t = (tid >= off) ? sm[tid - off] : 0;
        __syncthreads();
        xv += t;
        sm[tid] = xv;
        __syncthreads();
    }
    if (tid < nb) bsum[tid] = xv - v;
}

__global__ void k_scanC(int* __restrict__ row_ptr, int* __restrict__ cursor,
                        const int* __restrict__ bsum, int n) {
    int i = blockIdx.x * blockDim.x + threadIdx.x;
    if (i < n) {
        int r = row_ptr[i] + bsum[i >> 10];
        row_ptr[i] = r;
        cursor[i] = r;
    }
}

__global__ void k_place8(const int* __restrict__ src, const int* __restrict__ dst,
                         int* cursor, int* __restrict__ srcid, int E) {
    int t = blockIdx.x * blockDim.x + threadIdx.x;
    int e0 = t * 8;
    if (e0 >= E) return;
    if (e0 + 8 <= E) {
        int4 sa = *(const int4*)(src + e0);
        int4 sb = *(const int4*)(src + e0 + 4);
        int4 da = *(const int4*)(dst + e0);
        int4 db = *(const int4*)(dst + e0 + 4);
        if (sa.x != da.x) srcid[atomicAdd(&cursor[da.x], 1)] = sa.x;
        if (sa.y != da.y) srcid[atomicAdd(&cursor[da.y], 1)] = sa.y;
        if (sa.z != da.z) srcid[atomicAdd(&cursor[da.z], 1)] = sa.z;
        if (sa.w != da.w) srcid[atomicAdd(&cursor[da.w], 1)] = sa.w;
        if (sb.x != db.x) srcid[atomicAdd(&cursor[db.x], 1)] = sb.x;
        if (sb.y != db.y) srcid[atomicAdd(&cursor[db.y], 1)] = sb.y;
        if (sb.z != db.z) srcid[atomicAdd(&cursor[db.z], 1)] = sb.z;
        if (sb.w != db.w) srcid[atomicAdd(&cursor[db.w], 1)] = sb.w;
    } else {
        for (int e = e0; e < E; ++e) {
            int s = src[e], d = dst[e];
            if (s != d) srcid[atomicAdd(&cursor[d], 1)] = s;
        }
    }
}

// ================= fused gather(bf16) + GEMM + BN stats =================
// 2 nodes per wave (32-lane halves); each lane owns 2 channels (uint = 2x bf16).
// 8-deep unroll -> up to 16 rows in flight per wave.
__global__ __launch_bounds__(256) void k_gather2(
        const int* __restrict__ row_ptr, const int* __restrict__ cnt,
        const int* __restrict__ srcid, const float* __restrict__ x,
        const ushort_t* __restrict__ xb, const float* __restrict__ dinv,
        const float* __restrict__ W, float* __restrict__ out, float* sums16, int n) {
    __shared__ float Ws[64 * 64];
    int tid = threadIdx.x;
    for (int i = tid; i < 64 * 64; i += 256) Ws[i] = W[i];
    __syncthreads();

    int wave = tid >> 6, lane = tid & 63;
    int sl = lane & 31;
    int half = lane >> 5;
    int c0 = sl * 2;
    int d = blockIdx.x * 8 + wave * 2 + half;
    bool valid = d < n;

    int base = 0, c = 0;
    float did = 0.0f;
    float2 self = {0.0f, 0.0f};
    if (valid) {
        base = row_ptr[d];
        c = cnt[d];
        did = dinv[d];
        self = *(const float2*)&x[(size_t)d * D + c0];
    }

    float2 acc = {0.0f, 0.0f};
    for (int j = 0; j < c; j += 8) {
        int si[8];
        uint_t rv[8];
#pragma unroll
        for (int u = 0; u < 8; ++u) {
            int idx = j + u;
            si[u] = srcid[base + (idx < c ? idx : c - 1)];
        }
#pragma unroll
        for (int u = 0; u < 8; ++u) {
            rv[u] = *(const uint_t*)&xb[(size_t)si[u] * D + c0];
        }
#pragma unroll
        for (int u = 0; u < 8; ++u) {
            if (j + u < c) {
                acc.x += b2f_lo(rv[u]);
                acc.y += b2f_hi(rv[u]);
            }
        }
    }

    float2 agg;
    agg.x = did * (did * self.x + acc.x);
    agg.y = did * (did * self.y + acc.y);

    // GEMM: out_row = agg_row @ W ; broadcast agg across the 32-lane half
    double pk = __hiloint2double(__float_as_int(agg.y), __float_as_int(agg.x));
    float2 o = {0.0f, 0.0f};
    int hb = lane & 32;
#pragma unroll
    for (int m = 0; m < 32; ++m) {
        double t = __shfl(pk, hb + m);
        float ax = __uint_as_float((uint_t)__double2loint(t));
        float ay = __uint_as_float((uint_t)__double2hiint(t));
        float2 w0 = *(const float2*)&Ws[(2 * m) * 64 + c0];
        float2 w1 = *(const float2*)&Ws[(2 * m + 1) * 64 + c0];
        o.x += ax * w0.x + ay * w1.x;
        o.y += ax * w0.y + ay * w1.y;
    }
    if (valid) *(float2*)&out[(size_t)d * D + c0] = o;

    // BN stats
    float2 s2 = valid ? o : make_float2(0.0f, 0.0f);
    float2 q2 = {s2.x * s2.x, s2.y * s2.y};
    __shared__ float2 ls[4][64], lq[4][64];
    ls[wave][lane] = s2;
    lq[wave][lane] = q2;
    __syncthreads();
    if (wave == 0 && lane < 32) {
        float2 ts = {0.0f, 0.0f}, tq = {0.0f, 0.0f};
#pragma unroll
        for (int w = 0; w < 4; ++w) {
            ts.x += ls[w][lane].x + ls[w][lane + 32].x;
            ts.y += ls[w][lane].y + ls[w][lane + 32].y;
            tq.x += lq[w][lane].x + lq[w][lane + 32].x;
            tq.y += lq[w][lane].y + lq[w][lane + 32].y;
        }
        float* slot = sums16 + (size_t)(blockIdx.x & 15) * 128;
        atomicAdd(&slot[c0], ts.x);
        atomicAdd(&slot[c0 + 1], ts.y);
        atomicAdd(&slot[64 + c0], tq.x);
        atomicAdd(&slot[64 + c0 + 1], tq.y);
    }
}

// fold 16 slots -> final sums (stored at sums16 + 2048)
__global__ void k_finalize(float* sums16) {
    int i = threadIdx.x;  // 128 threads
    float s = 0.0f;
#pragma unroll
    for (int j = 0; j < 16; ++j) s += sums16[j * 128 + i];
    sums16[2048 + i] = s;
}

// ================= BN apply + ReLU (float4, in place) =================
// GCN bias b cancels exactly in BatchNorm: omitted.
__global__ void k_bn_apply(float* out, const float* __restrict__ sums,
                           const float* __restrict__ bnw, const float* __restrict__ bnb,
                           int n) {
    int i = blockIdx.x * blockDim.x + threadIdx.x;
    int total = n * (D / 4);
    if (i >= total) return;
    int c0 = (i * 4) & 63;
    const float invn = 1.0f / (float)NN;
    float4 v = ((const float4*)out)[i];
    float r[4] = {v.x, v.y, v.z, v.w};
#pragma unroll
    for (int j = 0; j < 4; ++j) {
        int c = c0 + j;
        float mean = sums[c] * invn;
        float var = sums[64 + c] * invn - mean * mean;
        if (var < 0.0f) var = 0.0f;
        float scale = bnw[c] * rsqrtf(var + BN_EPS);
        float y = (r[j] - mean) * scale + bnb[c];
        r[j] = y > 0.0f ? y : 0.0f;
    }
    float4 o = {r[0], r[1], r[2], r[3]};
    ((float4*)out)[i] = o;
}

extern "C" void kernel_launch(void* const* d_in, const int* in_sizes, int n_in,
                              void* d_out, int out_size, void* d_ws, size_t ws_size,
                              hipStream_t stream) {
    const float* x = (const float*)d_in[0];
    const int* ei = (const int*)d_in[1];
    const float* W = (const float*)d_in[3];
    const float* bnw = (const float*)d_in[5];
    const float* bnb = (const float*)d_in[6];
    float* out = (float*)d_out;

    const int n = in_sizes[0] / D;   // 100000
    const int E = in_sizes[1] / 2;   // 1600000
    const int* src = ei;
    const int* dst = ei + E;

    int* cnt = (int*)d_ws;
    int* row_ptr = cnt + n;
    int* cursor = row_ptr + n;
    float* dinv = (float*)(cursor + n);
    int* srcid = (int*)(dinv + n);
    int* bsum = srcid + E;                  // 128 ints
    float* sums16 = (float*)(bsum + 128);   // 16*128 slots + 128 final
    float* sums = sums16 + 2048;
    size_t off = ((size_t)((char*)(sums16 + 2176) - (char*)d_ws) + 15) & ~(size_t)15;
    ushort_t* xb = (ushort_t*)((char*)d_ws + off);

    const int nb = (n + 1023) / 1024;  // 98

    k_zero<<<(n + 255) / 256, 256, 0, stream>>>(cnt, sums16, n);
    k_count8<<<((E + 7) / 8 + 255) / 256, 256, 0, stream>>>(src, dst, cnt, E);
    k_dinv_xb<<<(n * (D / 4) + 255) / 256, 256, 0, stream>>>(cnt, x, dinv, xb, n);
    k_scanA<<<nb, 1024, 0, stream>>>(cnt, row_ptr, bsum, n);
    k_scanB<<<1, 128, 0, stream>>>(bsum, nb);
    k_scanC<<<(n + 255) / 256, 256, 0, stream>>>(row_ptr, cursor, bsum, n);
    k_place8<<<((E + 7) / 8 + 255) / 256, 256, 0, stream>>>(src, dst, cursor, srcid, E);

    k_gather2<<<(n + 7) / 8, 256, 0, stream>>>(row_ptr, cnt, srcid, x, xb, dinv, W,
                                               out, sums16, n);
    k_finalize<<<1, 128, 0, stream>>>(sums16);
    k_bn_apply<<<(n * (D / 4) + 255) / 256, 256, 0, stream>>>(out, sums, bnw, bnb, n);
}